// Round 10
// baseline (901.037 us; speedup 1.0000x reference)
//
#include <hip/hip_runtime.h>

typedef unsigned short u16;
typedef u16 u16x8 __attribute__((ext_vector_type(8)));
typedef float f32x4v __attribute__((ext_vector_type(4)));
typedef __bf16 bf16x8 __attribute__((ext_vector_type(8)));

// ---------- helpers ----------
__device__ __forceinline__ u16 f2bf(float f) {
  unsigned u = __builtin_bit_cast(unsigned, f);
  u += 0x7fffu + ((u >> 16) & 1u);  // round-to-nearest-even
  return (u16)(u >> 16);
}
__device__ __forceinline__ float bf2f(u16 b) {
  return __builtin_bit_cast(float, (unsigned)b << 16);
}

// ---------- fp32 -> bf16 conversion ----------
__global__ __launch_bounds__(256) void cvt_f32_bf16(const float* __restrict__ in,
                                                    u16* __restrict__ out, long n) {
  long i0 = ((long)blockIdx.x * 256 + threadIdx.x) * 8;
  long stride = (long)gridDim.x * 256 * 8;
  for (long i = i0; i < n; i += stride) {
    float4 a = *(const float4*)(in + i);
    float4 b = *(const float4*)(in + i + 4);
    u16x8 o;
    o[0] = f2bf(a.x); o[1] = f2bf(a.y); o[2] = f2bf(a.z); o[3] = f2bf(a.w);
    o[4] = f2bf(b.x); o[5] = f2bf(b.y); o[6] = f2bf(b.z); o[7] = f2bf(b.w);
    *(u16x8*)(out + i) = o;
  }
}

// ---------- 128x128 GEMM: A reg-staged -> 3-slot LDS ring, B direct to registers ----------
// ALL VMEM ops are per-lane register loads -> every load->use wait is compiler-tracked
// (no manual vmcnt, no cross-class FIFO assumptions — the R9 failure class is gone).
// LDS 24 KiB: A slot s=H%3 at s*4096 u16, [128 rows][32 k] bf16, chunk-swizzled
//   (LDS chunk c of row r holds global chunk c ^ ((r>>1)&3); reads de-swizzle).
// Phase H: { load B(H+1)->regs [4]; load A(H+2)->regs [2]; ds_read af(H) [4];
//            MFMA(af, B(H) regs); ds_write A(H+1) regs -> slot (H+1)%3;
//            lgkmcnt(0); s_barrier; sched_barrier(0) }
// Slot safety: slot (H+1)%3's old content A(H-2) was last ds_read in phase H-2 and
// retired before that phase's end barrier — 2 barriers before this write.
// Visibility: each wave's writes retired at its lgkmcnt(0) before the barrier; next
// phase's ds_reads cannot hoist above the barrier (sched_barrier(0) + asm clobber).
// A-reg pipeline: load A(H+2) in phase H, ds_write in phase H+1, ds_read in phase H+2.
template <int EPI>
__global__ __launch_bounds__(256, 3) void gemm128(
    const u16* __restrict__ A, long lda, long bsA,
    const u16* __restrict__ B, long ldb, long bsB,
    void* __restrict__ Cv, long ldc, long bsC, int K,
    const int* __restrict__ maskp, float scale,
    const float* __restrict__ bias, float* __restrict__ aux) {
  __shared__ u16 sm[12288];
  const int t = threadIdx.x;
  const int lane = t & 63;
  const int w = t >> 6;
  const int wr = w >> 1;   // 0..1 : 64-row group
  const int wc = w & 1;    // 0..1 : 64-col group

  const int bx = blockIdx.x;
  const int by = blockIdx.y;
  const int bz = blockIdx.z;

  // A staging sources (LDS dest linear t*16B; source pre-swizzled)
  const u16* Ab = A + (long)bz * bsA + (long)bx * 128 * lda;
  const int srow = t >> 2;
  const int scw = ((t & 3) ^ ((srow >> 1) & 3)) * 8;
  const u16* gA  = Ab + (long)srow * lda + scw;   // rows 0..63
  const u16* gAh = gA + 64 * lda;                 // rows 64..127 (same xor term)

  // B fragment pointers: lane reads row (by*128 + wc*64 + (lane&15) + fc*16),
  // k-chunk (lane>>4)*8 (+ H*32 per phase); 4 lanes share each 64B line.
  const u16* bp[4];
  {
    const u16* Bw = B + (long)bz * bsB +
                    ((long)by * 128 + wc * 64 + (lane & 15)) * ldb + (lane >> 4) * 8;
#pragma unroll
    for (int fc = 0; fc < 4; ++fc) bp[fc] = Bw + (long)fc * 16 * ldb;
  }

  f32x4v acc[4][4];
#pragma unroll
  for (int i = 0; i < 4; ++i)
#pragma unroll
    for (int j = 0; j < 4; ++j) acc[i][j] = (f32x4v){0.f, 0.f, 0.f, 0.f};

  // ds_read fragment addressing ((r>>1)&3 is fr-invariant: fr steps rows by 16)
  const int rA0 = wr * 64 + (lane & 15);
  const int aoffb = rA0 * 32 + (((lane >> 4) ^ ((rA0 >> 1) & 3)) * 8);

  const int NH = K >> 5;  // 32-k halves; 32/64/32 here — always even

  bf16x8 bA[4], bB[4];            // B double-buffer (named sets)
  bf16x8 rsA0, rsA1, rsB0, rsB1;  // A stage regs, two named sets

  // ---- prologue: A(0)->rsA, A(1)->rsB, B(0)->bA; write A(0)->slot0 ----
  rsA0 = *(const bf16x8*)(gA);
  rsA1 = *(const bf16x8*)(gAh);
  rsB0 = *(const bf16x8*)(gA + 32);
  rsB1 = *(const bf16x8*)(gAh + 32);
#pragma unroll
  for (int fc = 0; fc < 4; ++fc) bA[fc] = *(const bf16x8*)(bp[fc]);
  *(bf16x8*)(sm + t * 8) = rsA0;          // compiler waits rsA0 loads
  *(bf16x8*)(sm + 2048 + t * 8) = rsA1;
  asm volatile("s_waitcnt lgkmcnt(0)" ::: "memory");
  __builtin_amdgcn_s_barrier();
  __builtin_amdgcn_sched_barrier(0);

// even H: consume bA, load bB=B(H+1); write rsB=A(H+1); load rsA=A(H+2)
// odd  H: swap roles.
#define PHASE(H, BC, BN, W0, W1, L0, L1)                                        \
  {                                                                             \
    const int slotb = ((H) % 3) * 4096;                                         \
    if ((H) + 1 < NH) {                                                         \
      _Pragma("unroll") for (int fc = 0; fc < 4; ++fc)                          \
          BN[fc] = *(const bf16x8*)(bp[fc] + ((H) + 1) * 32);                   \
    }                                                                           \
    if ((H) + 2 < NH) {                                                         \
      L0 = *(const bf16x8*)(gA + ((H) + 2) * 32);                               \
      L1 = *(const bf16x8*)(gAh + ((H) + 2) * 32);                              \
    }                                                                           \
    bf16x8 af[4];                                                               \
    _Pragma("unroll") for (int fr = 0; fr < 4; ++fr)                            \
        af[fr] = *(const bf16x8*)(sm + slotb + aoffb + fr * 512);               \
    __builtin_amdgcn_s_setprio(1);                                              \
    _Pragma("unroll") for (int fr = 0; fr < 4; ++fr)                            \
        _Pragma("unroll") for (int fc = 0; fc < 4; ++fc)                        \
            acc[fr][fc] = __builtin_amdgcn_mfma_f32_16x16x32_bf16(              \
                af[fr], BC[fc], acc[fr][fc], 0, 0, 0);                          \
    __builtin_amdgcn_s_setprio(0);                                              \
    if ((H) + 1 < NH) {                                                         \
      const int ws = (((H) + 1) % 3) * 4096;                                    \
      *(bf16x8*)(sm + ws + t * 8) = W0;                                         \
      *(bf16x8*)(sm + ws + 2048 + t * 8) = W1;                                  \
    }                                                                           \
    asm volatile("s_waitcnt lgkmcnt(0)" ::: "memory");                          \
    __builtin_amdgcn_s_barrier();                                               \
    __builtin_amdgcn_sched_barrier(0);                                          \
  }

  for (int H = 0; H < NH; H += 2) {
    PHASE(H, bA, bB, rsB0, rsB1, rsA0, rsA1);
    PHASE(H + 1, bB, bA, rsA0, rsA1, rsB0, rsB1);
  }
#undef PHASE

  // ---- epilogue: C/D layout col = lane&15, row = (lane>>4)*4 + reg ----
  const long row0 = (long)bx * 128 + wr * 64;
  const long col0 = (long)by * 128 + wc * 64;
  const int l4 = lane >> 4;
  const int cl = lane & 15;
  if constexpr (EPI == 0) {
    u16* C = (u16*)Cv + (long)bz * bsC;
    const int* mrow = maskp + (long)bz * 2048;
    int mk4[4];
#pragma unroll
    for (int fc = 0; fc < 4; ++fc) mk4[fc] = mrow[col0 + fc * 16 + cl];
#pragma unroll
    for (int fr = 0; fr < 4; ++fr) {
#pragma unroll
      for (int r = 0; r < 4; ++r) {
        long row = row0 + fr * 16 + l4 * 4 + r;
        float s = 0.f;
#pragma unroll
        for (int fc = 0; fc < 4; ++fc) {
          long col = col0 + fc * 16 + cl;
          float e = mk4[fc] ? __expf(acc[fr][fc][r] * scale + 1e-13f) : 1.0f;
          u16 eb = f2bf(e);
          C[row * ldc + col] = eb;
          s += bf2f(eb);  // sum the rounded value (consistent with E)
        }
        s += __shfl_xor(s, 1);
        s += __shfl_xor(s, 2);
        s += __shfl_xor(s, 4);
        s += __shfl_xor(s, 8);
        if (cl == 0) aux[((long)bz * 2048 + row) * 32 + by * 2 + wc] = s;
      }
    }
  } else if constexpr (EPI == 1) {
    u16* C = (u16*)Cv + (long)bz * bsC;
    const float* linv = aux + (long)bz * 2048;
#pragma unroll
    for (int fr = 0; fr < 4; ++fr) {
#pragma unroll
      for (int r = 0; r < 4; ++r) {
        long row = row0 + fr * 16 + l4 * 4 + r;
        float li = linv[row];
#pragma unroll
        for (int fc = 0; fc < 4; ++fc) {
          long col = col0 + fc * 16 + cl;
          C[row * ldc + col] = f2bf(acc[fr][fc][r] * li);
        }
      }
    }
  } else {
    float* C = (float*)Cv;
#pragma unroll
    for (int fc = 0; fc < 4; ++fc) {
      long col = col0 + fc * 16 + cl;
      float bj = bias[col];
#pragma unroll
      for (int fr = 0; fr < 4; ++fr) {
        long row = row0 + fr * 16 + l4 * 4;
#pragma unroll
        for (int r = 0; r < 4; ++r) C[(row + r) * ldc + col] = acc[fr][fc][r] + bj;
      }
    }
  }
}

// ---------- per-row 1/sum of 32 partials ----------
__global__ __launch_bounds__(256) void rowsum_inv(const float* __restrict__ part,
                                                  float* __restrict__ linv) {
  int i = blockIdx.x * 256 + threadIdx.x;  // 0..32767
  const float4* p = (const float4*)(part + (long)i * 32);
  float s = 0.f;
#pragma unroll
  for (int j = 0; j < 8; ++j) {
    float4 v = p[j];
    s += (v.x + v.y) + (v.z + v.w);
  }
  linv[i] = 1.0f / s;
}

// ---------- launcher ----------
extern "C" void kernel_launch(void* const* d_in, const int* in_sizes, int n_in,
                              void* d_out, int out_size, void* d_ws, size_t ws_size,
                              hipStream_t stream) {
  const float* Q = (const float*)d_in[0];
  const float* K = (const float*)d_in[1];
  const float* V = (const float*)d_in[2];
  const int* mask = (const int*)d_in[3];
  const float* W = (const float*)d_in[4];
  const float* bias = (const float*)d_in[5];

  const long NQ = 16L * 2048 * 1024;       // 33,554,432
  u16* Qb = (u16*)d_ws;
  u16* Kb = Qb + NQ;
  u16* Vb = Kb + NQ;
  u16* Wb = Vb + NQ;                        // 1M u16
  u16* Eb = Wb + 1024L * 1024;              // [16][2048][2048] bf16 (134 MB)
  float* Part = (float*)(Eb + 16L * 2048 * 2048);  // [16*2048][32] f32 (4 MB)
  float* Linv = Part + 32768L * 32;         // [16*2048] f32
  u16* R = Qb;                              // alias: Qb dead after GEMM1

  cvt_f32_bf16<<<2048, 256, 0, stream>>>(Q, Qb, NQ);
  cvt_f32_bf16<<<2048, 256, 0, stream>>>(K, Kb, NQ);
  cvt_f32_bf16<<<2048, 256, 0, stream>>>(V, Vb, NQ);
  cvt_f32_bf16<<<512, 256, 0, stream>>>(W, Wb, 1024L * 1024);

  // E = exp(QK^T*scale+1e-13) (masked cols -> 1.0), bf16 + per-row partial sums
  gemm128<0><<<dim3(16, 16, 16), 256, 0, stream>>>(
      Qb, 1024, 2048L * 1024, Kb, 1024, 2048L * 1024,
      Eb, 2048, 2048L * 2048, 1024, mask, 0.03125f, nullptr, Part);

  rowsum_inv<<<128, 256, 0, stream>>>(Part, Linv);

  // R = (E V^T) * Linv[row], bf16
  gemm128<1><<<dim3(16, 8, 16), 256, 0, stream>>>(
      Eb, 2048, 2048L * 2048, Vb, 2048, 1024L * 2048,
      R, 1024, 2048L * 1024, 2048, nullptr, 1.f, nullptr, Linv);

  // out = R W^T + bias
  gemm128<2><<<dim3(256, 8, 1), 256, 0, stream>>>(
      R, 1024, 0, Wb, 1024, 0,
      d_out, 1024, 0, 1024, nullptr, 1.f, bias, nullptr);
}

// Round 11
// 511.078 us; speedup vs baseline: 1.7630x; 1.7630x over previous
//
#include <hip/hip_runtime.h>

typedef unsigned short u16;
typedef u16 u16x8 __attribute__((ext_vector_type(8)));
typedef float f32x4v __attribute__((ext_vector_type(4)));
typedef __bf16 bf16x8 __attribute__((ext_vector_type(8)));

// ---------- helpers ----------
__device__ __forceinline__ u16 f2bf(float f) {
  unsigned u = __builtin_bit_cast(unsigned, f);
  u += 0x7fffu + ((u >> 16) & 1u);  // round-to-nearest-even
  return (u16)(u >> 16);
}
__device__ __forceinline__ float bf2f(u16 b) {
  return __builtin_bit_cast(float, (unsigned)b << 16);
}

// ---------- fp32 -> bf16 conversion ----------
__global__ __launch_bounds__(256) void cvt_f32_bf16(const float* __restrict__ in,
                                                    u16* __restrict__ out, long n) {
  long i0 = ((long)blockIdx.x * 256 + threadIdx.x) * 8;
  long stride = (long)gridDim.x * 256 * 8;
  for (long i = i0; i < n; i += stride) {
    float4 a = *(const float4*)(in + i);
    float4 b = *(const float4*)(in + i + 4);
    u16x8 o;
    o[0] = f2bf(a.x); o[1] = f2bf(a.y); o[2] = f2bf(a.z); o[3] = f2bf(a.w);
    o[4] = f2bf(b.x); o[5] = f2bf(b.y); o[6] = f2bf(b.z); o[7] = f2bf(b.w);
    *(u16x8*)(out + i) = o;
  }
}

// ---------- 256x256 GEMM, m201-faithful 8-phase schedule ----------
// A[M,K] x B[N,K]^T. BK=64, 8 waves (wr 0..1, wc 0..3), wave tile 128x64.
// LDS 128KiB (u16 units): A half (d,h) at (d*2+h)*8192 ; B at 32768 + (d*2+h)*8192.
//   Each half = [128 rows][64 k] bf16, 16KB, staged by 512 thr x 2 gload_lds (dest t*16B
//   and +8KB — m104-legal). Swizzle: slot chunk c of row r holds global chunk c^(r&7).
// Window w computes tiles t0=2w (dbuf0), t1=2w+1 (dbuf1) in 8 phases (quadrants
//   (rh,ch) = (0,0),(0,1),(1,1),(1,0) per tile); per phase: ds_read regs -> [lgkm(8)]
//   -> barrier -> lgkm(0) -> sched_barrier -> 16 MFMA -> [vmcnt] -> barrier.
// Stages (1 half = 2 gloads per phase): p1:t1.A0 p2:t1.A1 p3:t2.B0 p4:t2.B1
//   p5:t2.A0 p6:t2.A1 p7:t3.B0 p8:t3.B1   (t2=2w+2, t3=2w+3; guarded by w<nw-1).
// Slot safety (1+ barrier after death): B halves die p2/p6, A halves die p3/p7.
// vmcnt(4) at p4 (guarantees t1.A0,A1 landed; leaves t2.B0,B1) and p8 (guarantees all
//   t2 landed; leaves t3.B0,B1). Last window: p4 -> vmcnt(0), p8 -> skip.
// Prologue: t0.{B0,B1,A0,A1} + t1.{B0,B1} (12 loads), vmcnt(4) -> t0 landed.
template <int EPI>
__global__ __launch_bounds__(512, 2) void gemm256(
    const u16* __restrict__ A, long lda, long bsA,
    const u16* __restrict__ B, long ldb, long bsB,
    void* __restrict__ Cv, long ldc, long bsC, int K,
    const int* __restrict__ maskp, float scale,
    const float* __restrict__ bias, float* __restrict__ aux) {
  extern __shared__ u16 sm[];
  const int t = threadIdx.x;
  const int lane = t & 63;
  const int w8 = t >> 6;
  const int wr = w8 >> 2;  // 0..1
  const int wc = w8 & 3;   // 0..3

  const int bx = blockIdx.x, by = blockIdx.y, bz = blockIdx.z;

  // staging sources: thread t covers row sr (and sr+64) of a half, chunk (t&7)^(sr&7)
  const int sr = t >> 3;
  const int sc = ((t & 7) ^ (sr & 7)) * 8;
  const u16* gA_ = A + (long)bz * bsA + ((long)bx * 256 + sr) * lda + sc;
  const u16* gB_ = B + (long)bz * bsB + ((long)by * 256 + sr) * ldb + sc;

#define GLDS(gptr, lidx)                                                        \
  __builtin_amdgcn_global_load_lds(                                             \
      (const __attribute__((address_space(1))) void*)(gptr),                    \
      (__attribute__((address_space(3))) void*)(sm + (lidx)), 16, 0, 0)

#define STG_A(d, h, kt)                                                         \
  do {                                                                          \
    const int bb = ((d)*2 + (h)) * 8192;                                        \
    const long ko = (long)(kt)*64;                                              \
    GLDS(gA_ + (long)((h)*128) * lda + ko, bb + t * 8);                         \
    GLDS(gA_ + (long)((h)*128 + 64) * lda + ko, bb + 4096 + t * 8);             \
  } while (0)
#define STG_B(d, h, kt)                                                         \
  do {                                                                          \
    const int bb = 32768 + ((d)*2 + (h)) * 8192;                                \
    const long ko = (long)(kt)*64;                                              \
    GLDS(gB_ + (long)((h)*128) * ldb + ko, bb + t * 8);                         \
    GLDS(gB_ + (long)((h)*128 + 64) * ldb + ko, bb + 4096 + t * 8);             \
  } while (0)

  f32x4v acc[8][4];
#pragma unroll
  for (int i = 0; i < 8; ++i)
#pragma unroll
    for (int j = 0; j < 4; ++j) acc[i][j] = (f32x4v){0.f, 0.f, 0.f, 0.f};

  // frag read offsets (u16): row lr, k-chunk c=ks*4+g, phys = c ^ (lr&7); lr&7 == lane&7
  const int g = lane >> 4;       // 0..3
  const int s3 = lane & 7;
  const int rl = lane & 15;
  const int ox0 = ((0 * 4 + g) ^ s3) * 8;
  const int ox1 = ((1 * 4 + g) ^ s3) * 8;
  const int oa0 = rl * 64 + ox0, oa1 = rl * 64 + ox1;
  const int obb = (wc & 1) * 4096 + rl * 64;  // within B half: (wc&1)*64 rows + rl

  bf16x8 af[4][2], bq[4][2];

#define RD_A(d, rh)                                                             \
  do {                                                                          \
    const int ab = ((d)*2 + wr) * 8192 + (rh)*4096;                             \
    _Pragma("unroll") for (int j = 0; j < 4; ++j) {                             \
      af[j][0] = *(const bf16x8*)(sm + ab + j * 1024 + oa0);                    \
      af[j][1] = *(const bf16x8*)(sm + ab + j * 1024 + oa1);                    \
    }                                                                           \
  } while (0)
#define RD_B(d, ch)                                                             \
  do {                                                                          \
    const int bb = 32768 + ((d)*2 + (wc >> 1)) * 8192 + obb;                    \
    _Pragma("unroll") for (int i = 0; i < 2; ++i) {                             \
      bq[(ch)*2 + i][0] = *(const bf16x8*)(sm + bb + ((ch)*2 + i) * 1024 + ox0);\
      bq[(ch)*2 + i][1] = *(const bf16x8*)(sm + bb + ((ch)*2 + i) * 1024 + ox1);\
    }                                                                           \
  } while (0)
#define DO_MFMA(rh, ch)                                                         \
  do {                                                                          \
    __builtin_amdgcn_s_setprio(1);                                              \
    _Pragma("unroll") for (int j = 0; j < 4; ++j)                               \
        _Pragma("unroll") for (int i = 0; i < 2; ++i) {                         \
      acc[(rh)*4 + j][(ch)*2 + i] = __builtin_amdgcn_mfma_f32_16x16x32_bf16(    \
          af[j][0], bq[(ch)*2 + i][0], acc[(rh)*4 + j][(ch)*2 + i], 0, 0, 0);   \
      acc[(rh)*4 + j][(ch)*2 + i] = __builtin_amdgcn_mfma_f32_16x16x32_bf16(    \
          af[j][1], bq[(ch)*2 + i][1], acc[(rh)*4 + j][(ch)*2 + i], 0, 0, 0);   \
    }                                                                           \
    __builtin_amdgcn_s_setprio(0);                                              \
  } while (0)

#define BAR __builtin_amdgcn_s_barrier()
#define LGKM0                                                                   \
  asm volatile("s_waitcnt lgkmcnt(0)" ::: "memory");                            \
  __builtin_amdgcn_sched_barrier(0)
#define LGKM8 asm volatile("s_waitcnt lgkmcnt(8)" ::: "memory")

  const int nw = K >> 7;  // windows of 2 K-tiles

  // ---- prologue ----
  STG_B(0, 0, 0); STG_B(0, 1, 0);
  STG_A(0, 0, 0); STG_A(0, 1, 0);
  STG_B(1, 0, 1); STG_B(1, 1, 1);
  asm volatile("s_waitcnt vmcnt(4)" ::: "memory");
  BAR;

  for (int w = 0; w < nw; ++w) {
    const int kt1 = 2 * w + 1;
    const bool nx = (w + 1 < nw);
    // ---- p1: t0 q(0,0) ; stage t1.A0 ----
    RD_A(0, 0); RD_B(0, 0);
    STG_A(1, 0, kt1);
    LGKM8; BAR; LGKM0;
    DO_MFMA(0, 0);
    BAR;
    // ---- p2: t0 q(0,1) ; stage t1.A1 ----
    RD_B(0, 1);
    STG_A(1, 1, kt1);
    BAR; LGKM0;
    DO_MFMA(0, 1);
    BAR;
    // ---- p3: t0 q(1,1) ; stage t2.B0 ----
    RD_A(0, 1);
    if (nx) STG_B(0, 0, kt1 + 1);
    BAR; LGKM0;
    DO_MFMA(1, 1);
    BAR;
    // ---- p4: t0 q(1,0) ; stage t2.B1 ; vmcnt ----
    if (nx) STG_B(0, 1, kt1 + 1);
    BAR; LGKM0;
    DO_MFMA(1, 0);
    if (nx) asm volatile("s_waitcnt vmcnt(4)" ::: "memory");
    else    asm volatile("s_waitcnt vmcnt(0)" ::: "memory");
    BAR;
    // ---- p5: t1 q(0,0) ; stage t2.A0 ----
    RD_A(1, 0); RD_B(1, 0);
    if (nx) STG_A(0, 0, kt1 + 1);
    LGKM8; BAR; LGKM0;
    DO_MFMA(0, 0);
    BAR;
    // ---- p6: t1 q(0,1) ; stage t2.A1 ----
    RD_B(1, 1);
    if (nx) STG_A(0, 1, kt1 + 1);
    BAR; LGKM0;
    DO_MFMA(0, 1);
    BAR;
    // ---- p7: t1 q(1,1) ; stage t3.B0 ----
    RD_A(1, 1);
    if (nx) STG_B(1, 0, kt1 + 2);
    BAR; LGKM0;
    DO_MFMA(1, 1);
    BAR;
    // ---- p8: t1 q(1,0) ; stage t3.B1 ; vmcnt ----
    if (nx) STG_B(1, 1, kt1 + 2);
    BAR; LGKM0;
    DO_MFMA(1, 0);
    if (nx) asm volatile("s_waitcnt vmcnt(4)" ::: "memory");
    BAR;
  }
#undef STG_A
#undef STG_B
#undef GLDS

  // ---- epilogue: C/D layout col = lane&15, row = (lane>>4)*4 + reg ----
  const long row0 = (long)bx * 256 + wr * 128;
  const long col0 = (long)by * 256 + wc * 64;
  const int l4 = lane >> 4;
  const int cl = lane & 15;
  if constexpr (EPI == 0) {
    u16* C = (u16*)Cv + (long)bz * bsC;
    const int* mrow = maskp + (long)bz * 2048;
    int mk4[4];
#pragma unroll
    for (int fc = 0; fc < 4; ++fc) mk4[fc] = mrow[col0 + fc * 16 + cl];
#pragma unroll
    for (int fr = 0; fr < 8; ++fr) {
#pragma unroll
      for (int r = 0; r < 4; ++r) {
        long row = row0 + fr * 16 + l4 * 4 + r;
        float s = 0.f;
#pragma unroll
        for (int fc = 0; fc < 4; ++fc) {
          long col = col0 + fc * 16 + cl;
          float e = mk4[fc] ? __expf(acc[fr][fc][r] * scale + 1e-13f) : 1.0f;
          u16 eb = f2bf(e);
          C[row * ldc + col] = eb;
          s += bf2f(eb);
        }
        s += __shfl_xor(s, 1);
        s += __shfl_xor(s, 2);
        s += __shfl_xor(s, 4);
        s += __shfl_xor(s, 8);
        if (cl == 0) aux[((long)bz * 2048 + row) * 32 + by * 4 + wc] = s;
      }
    }
  } else if constexpr (EPI == 1) {
    u16* C = (u16*)Cv + (long)bz * bsC;
    const float* linv = aux + (long)bz * 2048;
#pragma unroll
    for (int fr = 0; fr < 8; ++fr) {
#pragma unroll
      for (int r = 0; r < 4; ++r) {
        long row = row0 + fr * 16 + l4 * 4 + r;
        float li = linv[row];
#pragma unroll
        for (int fc = 0; fc < 4; ++fc) {
          long col = col0 + fc * 16 + cl;
          C[row * ldc + col] = f2bf(acc[fr][fc][r] * li);
        }
      }
    }
  } else {
    float* C = (float*)Cv;
#pragma unroll
    for (int fc = 0; fc < 4; ++fc) {
      long col = col0 + fc * 16 + cl;
      float bj = bias[col];
#pragma unroll
      for (int fr = 0; fr < 8; ++fr) {
        long row = row0 + fr * 16 + l4 * 4;
#pragma unroll
        for (int r = 0; r < 4; ++r) C[(row + r) * ldc + col] = acc[fr][fc][r] + bj;
      }
    }
  }
}

// ---------- per-row 1/sum of 32 partials ----------
__global__ __launch_bounds__(256) void rowsum_inv(const float* __restrict__ part,
                                                  float* __restrict__ linv) {
  int i = blockIdx.x * 256 + threadIdx.x;  // 0..32767
  const float4* p = (const float4*)(part + (long)i * 32);
  float s = 0.f;
#pragma unroll
  for (int j = 0; j < 8; ++j) {
    float4 v = p[j];
    s += (v.x + v.y) + (v.z + v.w);
  }
  linv[i] = 1.0f / s;
}

// ---------- launcher ----------
extern "C" void kernel_launch(void* const* d_in, const int* in_sizes, int n_in,
                              void* d_out, int out_size, void* d_ws, size_t ws_size,
                              hipStream_t stream) {
  const float* Q = (const float*)d_in[0];
  const float* K = (const float*)d_in[1];
  const float* V = (const float*)d_in[2];
  const int* mask = (const int*)d_in[3];
  const float* W = (const float*)d_in[4];
  const float* bias = (const float*)d_in[5];

  const long NQ = 16L * 2048 * 1024;
  u16* Qb = (u16*)d_ws;
  u16* Kb = Qb + NQ;
  u16* Vb = Kb + NQ;
  u16* Wb = Vb + NQ;
  u16* Eb = Wb + 1024L * 1024;                     // [16][2048][2048] bf16
  float* Part = (float*)(Eb + 16L * 2048 * 2048);  // [16*2048][32] f32
  float* Linv = Part + 32768L * 32;                // [16*2048] f32
  u16* R = Qb;                                     // alias: Qb dead after GEMM1

  cvt_f32_bf16<<<2048, 256, 0, stream>>>(Q, Qb, NQ);
  cvt_f32_bf16<<<2048, 256, 0, stream>>>(K, Kb, NQ);
  cvt_f32_bf16<<<2048, 256, 0, stream>>>(V, Vb, NQ);
  cvt_f32_bf16<<<512, 256, 0, stream>>>(W, Wb, 1024L * 1024);

  // E = exp(QK^T*scale+1e-13) (masked cols -> 1.0), bf16 + per-row partial sums
  gemm256<0><<<dim3(8, 8, 16), 512, 131072, stream>>>(
      Qb, 1024, 2048L * 1024, Kb, 1024, 2048L * 1024,
      Eb, 2048, 2048L * 2048, 1024, mask, 0.03125f, nullptr, Part);

  rowsum_inv<<<128, 256, 0, stream>>>(Part, Linv);

  // R = (E V^T) * Linv[row], bf16
  gemm256<1><<<dim3(8, 4, 16), 512, 131072, stream>>>(
      Eb, 2048, 2048L * 2048, Vb, 2048, 1024L * 2048,
      R, 1024, 2048L * 1024, 2048, nullptr, 1.f, nullptr, Linv);

  // out = R W^T + bias
  gemm256<2><<<dim3(128, 4, 1), 512, 131072, stream>>>(
      R, 1024, 0, Wb, 1024, 0,
      d_out, 1024, 0, 1024, nullptr, 1.f, bias, nullptr);
}

// Round 12
// 487.626 us; speedup vs baseline: 1.8478x; 1.0481x over previous
//
#include <hip/hip_runtime.h>

typedef unsigned short u16;
typedef u16 u16x8 __attribute__((ext_vector_type(8)));
typedef float f32x4v __attribute__((ext_vector_type(4)));
typedef __bf16 bf16x8 __attribute__((ext_vector_type(8)));

// ---------- helpers ----------
__device__ __forceinline__ u16 f2bf(float f) {
  unsigned u = __builtin_bit_cast(unsigned, f);
  u += 0x7fffu + ((u >> 16) & 1u);  // round-to-nearest-even
  return (u16)(u >> 16);
}
__device__ __forceinline__ float bf2f(u16 b) {
  return __builtin_bit_cast(float, (unsigned)b << 16);
}

// ---------- fp32 -> bf16 conversion ----------
__global__ __launch_bounds__(256) void cvt_f32_bf16(const float* __restrict__ in,
                                                    u16* __restrict__ out, long n) {
  long i0 = ((long)blockIdx.x * 256 + threadIdx.x) * 8;
  long stride = (long)gridDim.x * 256 * 8;
  for (long i = i0; i < n; i += stride) {
    float4 a = *(const float4*)(in + i);
    float4 b = *(const float4*)(in + i + 4);
    u16x8 o;
    o[0] = f2bf(a.x); o[1] = f2bf(a.y); o[2] = f2bf(a.z); o[3] = f2bf(a.w);
    o[4] = f2bf(b.x); o[5] = f2bf(b.y); o[6] = f2bf(b.z); o[7] = f2bf(b.w);
    *(u16x8*)(out + i) = o;
  }
}

// ---------- 256x256 GEMM, m201-faithful 8-phase schedule + T1 XCD swizzle ----------
// (R11 kernel byte-identical except the block-id remap — single-variable A/B.)
// A[M,K] x B[N,K]^T. BK=64, 8 waves (wr 0..1, wc 0..3), wave tile 128x64.
// LDS 128KiB: A half (d,h) at (d*2+h)*8192 u16 ; B at 32768 + (d*2+h)*8192.
// Swizzle: slot chunk c of row r holds global chunk c^(r&7) (involution).
// 8 phases / 2 K-tiles; stages p1:t1.A0 p2:t1.A1 p3:t2.B0 p4:t2.B1 p5:t2.A0
// p6:t2.A1 p7:t3.B0 p8:t3.B1 ; vmcnt(4) at p4/p8 (FIFO-exact, cover >= 2 phases).
template <int EPI>
__global__ __launch_bounds__(512, 2) void gemm256(
    const u16* __restrict__ A, long lda, long bsA,
    const u16* __restrict__ B, long ldb, long bsB,
    void* __restrict__ Cv, long ldc, long bsC, int K,
    const int* __restrict__ maskp, float scale,
    const float* __restrict__ bias, float* __restrict__ aux) {
  extern __shared__ u16 sm[];
  const int t = threadIdx.x;
  const int lane = t & 63;
  const int w8 = t >> 6;
  const int wr = w8 >> 2;  // 0..1
  const int wc = w8 & 3;   // 0..3

  // T1: bijective XCD-chunked remap (all grids here have nwg % 8 == 0)
  const int nwg = gridDim.x * gridDim.y * gridDim.z;
  int flat = blockIdx.x + gridDim.x * (blockIdx.y + gridDim.y * blockIdx.z);
  int nid = (flat & 7) * (nwg >> 3) + (flat >> 3);
  const int bx = nid % gridDim.x;
  const int by = (nid / gridDim.x) % gridDim.y;
  const int bz = nid / (gridDim.x * gridDim.y);

  // staging sources: thread t covers row sr (and sr+64) of a half, chunk (t&7)^(sr&7)
  const int sr = t >> 3;
  const int sc = ((t & 7) ^ (sr & 7)) * 8;
  const u16* gA_ = A + (long)bz * bsA + ((long)bx * 256 + sr) * lda + sc;
  const u16* gB_ = B + (long)bz * bsB + ((long)by * 256 + sr) * ldb + sc;

#define GLDS(gptr, lidx)                                                        \
  __builtin_amdgcn_global_load_lds(                                             \
      (const __attribute__((address_space(1))) void*)(gptr),                    \
      (__attribute__((address_space(3))) void*)(sm + (lidx)), 16, 0, 0)

#define STG_A(d, h, kt)                                                         \
  do {                                                                          \
    const int bb = ((d)*2 + (h)) * 8192;                                        \
    const long ko = (long)(kt)*64;                                              \
    GLDS(gA_ + (long)((h)*128) * lda + ko, bb + t * 8);                         \
    GLDS(gA_ + (long)((h)*128 + 64) * lda + ko, bb + 4096 + t * 8);             \
  } while (0)
#define STG_B(d, h, kt)                                                         \
  do {                                                                          \
    const int bb = 32768 + ((d)*2 + (h)) * 8192;                                \
    const long ko = (long)(kt)*64;                                              \
    GLDS(gB_ + (long)((h)*128) * ldb + ko, bb + t * 8);                         \
    GLDS(gB_ + (long)((h)*128 + 64) * ldb + ko, bb + 4096 + t * 8);             \
  } while (0)

  f32x4v acc[8][4];
#pragma unroll
  for (int i = 0; i < 8; ++i)
#pragma unroll
    for (int j = 0; j < 4; ++j) acc[i][j] = (f32x4v){0.f, 0.f, 0.f, 0.f};

  // frag read offsets (u16): row lr, k-chunk c, phys = c ^ (lr&7)
  const int g = lane >> 4;
  const int s3 = lane & 7;
  const int rl = lane & 15;
  const int ox0 = ((0 * 4 + g) ^ s3) * 8;
  const int ox1 = ((1 * 4 + g) ^ s3) * 8;
  const int oa0 = rl * 64 + ox0, oa1 = rl * 64 + ox1;
  const int obb = (wc & 1) * 4096 + rl * 64;

  bf16x8 af[4][2], bq[4][2];

#define RD_A(d, rh)                                                             \
  do {                                                                          \
    const int ab = ((d)*2 + wr) * 8192 + (rh)*4096;                             \
    _Pragma("unroll") for (int j = 0; j < 4; ++j) {                             \
      af[j][0] = *(const bf16x8*)(sm + ab + j * 1024 + oa0);                    \
      af[j][1] = *(const bf16x8*)(sm + ab + j * 1024 + oa1);                    \
    }                                                                           \
  } while (0)
#define RD_B(d, ch)                                                             \
  do {                                                                          \
    const int bb = 32768 + ((d)*2 + (wc >> 1)) * 8192 + obb;                    \
    _Pragma("unroll") for (int i = 0; i < 2; ++i) {                             \
      bq[(ch)*2 + i][0] = *(const bf16x8*)(sm + bb + ((ch)*2 + i) * 1024 + ox0);\
      bq[(ch)*2 + i][1] = *(const bf16x8*)(sm + bb + ((ch)*2 + i) * 1024 + ox1);\
    }                                                                           \
  } while (0)
#define DO_MFMA(rh, ch)                                                         \
  do {                                                                          \
    __builtin_amdgcn_s_setprio(1);                                              \
    _Pragma("unroll") for (int j = 0; j < 4; ++j)                               \
        _Pragma("unroll") for (int i = 0; i < 2; ++i) {                         \
      acc[(rh)*4 + j][(ch)*2 + i] = __builtin_amdgcn_mfma_f32_16x16x32_bf16(    \
          af[j][0], bq[(ch)*2 + i][0], acc[(rh)*4 + j][(ch)*2 + i], 0, 0, 0);   \
      acc[(rh)*4 + j][(ch)*2 + i] = __builtin_amdgcn_mfma_f32_16x16x32_bf16(    \
          af[j][1], bq[(ch)*2 + i][1], acc[(rh)*4 + j][(ch)*2 + i], 0, 0, 0);   \
    }                                                                           \
    __builtin_amdgcn_s_setprio(0);                                              \
  } while (0)

#define BAR __builtin_amdgcn_s_barrier()
#define LGKM0                                                                   \
  asm volatile("s_waitcnt lgkmcnt(0)" ::: "memory");                            \
  __builtin_amdgcn_sched_barrier(0)
#define LGKM8 asm volatile("s_waitcnt lgkmcnt(8)" ::: "memory")

  const int nw = K >> 7;  // windows of 2 K-tiles

  // ---- prologue ----
  STG_B(0, 0, 0); STG_B(0, 1, 0);
  STG_A(0, 0, 0); STG_A(0, 1, 0);
  STG_B(1, 0, 1); STG_B(1, 1, 1);
  asm volatile("s_waitcnt vmcnt(4)" ::: "memory");
  BAR;

  for (int w = 0; w < nw; ++w) {
    const int kt1 = 2 * w + 1;
    const bool nx = (w + 1 < nw);
    // ---- p1: t0 q(0,0) ; stage t1.A0 ----
    RD_A(0, 0); RD_B(0, 0);
    STG_A(1, 0, kt1);
    LGKM8; BAR; LGKM0;
    DO_MFMA(0, 0);
    BAR;
    // ---- p2: t0 q(0,1) ; stage t1.A1 ----
    RD_B(0, 1);
    STG_A(1, 1, kt1);
    BAR; LGKM0;
    DO_MFMA(0, 1);
    BAR;
    // ---- p3: t0 q(1,1) ; stage t2.B0 ----
    RD_A(0, 1);
    if (nx) STG_B(0, 0, kt1 + 1);
    BAR; LGKM0;
    DO_MFMA(1, 1);
    BAR;
    // ---- p4: t0 q(1,0) ; stage t2.B1 ; vmcnt ----
    if (nx) STG_B(0, 1, kt1 + 1);
    BAR; LGKM0;
    DO_MFMA(1, 0);
    if (nx) asm volatile("s_waitcnt vmcnt(4)" ::: "memory");
    else    asm volatile("s_waitcnt vmcnt(0)" ::: "memory");
    BAR;
    // ---- p5: t1 q(0,0) ; stage t2.A0 ----
    RD_A(1, 0); RD_B(1, 0);
    if (nx) STG_A(0, 0, kt1 + 1);
    LGKM8; BAR; LGKM0;
    DO_MFMA(0, 0);
    BAR;
    // ---- p6: t1 q(0,1) ; stage t2.A1 ----
    RD_B(1, 1);
    if (nx) STG_A(0, 1, kt1 + 1);
    BAR; LGKM0;
    DO_MFMA(0, 1);
    BAR;
    // ---- p7: t1 q(1,1) ; stage t3.B0 ----
    RD_A(1, 1);
    if (nx) STG_B(1, 0, kt1 + 2);
    BAR; LGKM0;
    DO_MFMA(1, 1);
    BAR;
    // ---- p8: t1 q(1,0) ; stage t3.B1 ; vmcnt ----
    if (nx) STG_B(1, 1, kt1 + 2);
    BAR; LGKM0;
    DO_MFMA(1, 0);
    if (nx) asm volatile("s_waitcnt vmcnt(4)" ::: "memory");
    BAR;
  }
#undef STG_A
#undef STG_B
#undef GLDS

  // ---- epilogue: C/D layout col = lane&15, row = (lane>>4)*4 + reg ----
  const long row0 = (long)bx * 256 + wr * 128;
  const long col0 = (long)by * 256 + wc * 64;
  const int l4 = lane >> 4;
  const int cl = lane & 15;
  if constexpr (EPI == 0) {
    u16* C = (u16*)Cv + (long)bz * bsC;
    const int* mrow = maskp + (long)bz * 2048;
    int mk4[4];
#pragma unroll
    for (int fc = 0; fc < 4; ++fc) mk4[fc] = mrow[col0 + fc * 16 + cl];
#pragma unroll
    for (int fr = 0; fr < 8; ++fr) {
#pragma unroll
      for (int r = 0; r < 4; ++r) {
        long row = row0 + fr * 16 + l4 * 4 + r;
        float s = 0.f;
#pragma unroll
        for (int fc = 0; fc < 4; ++fc) {
          long col = col0 + fc * 16 + cl;
          float e = mk4[fc] ? __expf(acc[fr][fc][r] * scale + 1e-13f) : 1.0f;
          u16 eb = f2bf(e);
          C[row * ldc + col] = eb;
          s += bf2f(eb);
        }
        s += __shfl_xor(s, 1);
        s += __shfl_xor(s, 2);
        s += __shfl_xor(s, 4);
        s += __shfl_xor(s, 8);
        if (cl == 0) aux[((long)bz * 2048 + row) * 32 + by * 4 + wc] = s;
      }
    }
  } else if constexpr (EPI == 1) {
    u16* C = (u16*)Cv + (long)bz * bsC;
    const float* linv = aux + (long)bz * 2048;
#pragma unroll
    for (int fr = 0; fr < 8; ++fr) {
#pragma unroll
      for (int r = 0; r < 4; ++r) {
        long row = row0 + fr * 16 + l4 * 4 + r;
        float li = linv[row];
#pragma unroll
        for (int fc = 0; fc < 4; ++fc) {
          long col = col0 + fc * 16 + cl;
          C[row * ldc + col] = f2bf(acc[fr][fc][r] * li);
        }
      }
    }
  } else {
    float* C = (float*)Cv;
#pragma unroll
    for (int fc = 0; fc < 4; ++fc) {
      long col = col0 + fc * 16 + cl;
      float bj = bias[col];
#pragma unroll
      for (int fr = 0; fr < 8; ++fr) {
        long row = row0 + fr * 16 + l4 * 4;
#pragma unroll
        for (int r = 0; r < 4; ++r) C[(row + r) * ldc + col] = acc[fr][fc][r] + bj;
      }
    }
  }
}

// ---------- per-row 1/sum of 32 partials ----------
__global__ __launch_bounds__(256) void rowsum_inv(const float* __restrict__ part,
                                                  float* __restrict__ linv) {
  int i = blockIdx.x * 256 + threadIdx.x;  // 0..32767
  const float4* p = (const float4*)(part + (long)i * 32);
  float s = 0.f;
#pragma unroll
  for (int j = 0; j < 8; ++j) {
    float4 v = p[j];
    s += (v.x + v.y) + (v.z + v.w);
  }
  linv[i] = 1.0f / s;
}

// ---------- launcher ----------
extern "C" void kernel_launch(void* const* d_in, const int* in_sizes, int n_in,
                              void* d_out, int out_size, void* d_ws, size_t ws_size,
                              hipStream_t stream) {
  const float* Q = (const float*)d_in[0];
  const float* K = (const float*)d_in[1];
  const float* V = (const float*)d_in[2];
  const int* mask = (const int*)d_in[3];
  const float* W = (const float*)d_in[4];
  const float* bias = (const float*)d_in[5];

  const long NQ = 16L * 2048 * 1024;
  u16* Qb = (u16*)d_ws;
  u16* Kb = Qb + NQ;
  u16* Vb = Kb + NQ;
  u16* Wb = Vb + NQ;
  u16* Eb = Wb + 1024L * 1024;                     // [16][2048][2048] bf16
  float* Part = (float*)(Eb + 16L * 2048 * 2048);  // [16*2048][32] f32
  float* Linv = Part + 32768L * 32;                // [16*2048] f32
  u16* R = Qb;                                     // alias: Qb dead after GEMM1

  cvt_f32_bf16<<<2048, 256, 0, stream>>>(Q, Qb, NQ);
  cvt_f32_bf16<<<2048, 256, 0, stream>>>(K, Kb, NQ);
  cvt_f32_bf16<<<2048, 256, 0, stream>>>(V, Vb, NQ);
  cvt_f32_bf16<<<512, 256, 0, stream>>>(W, Wb, 1024L * 1024);

  // E = exp(QK^T*scale+1e-13) (masked cols -> 1.0), bf16 + per-row partial sums
  gemm256<0><<<dim3(8, 8, 16), 512, 131072, stream>>>(
      Qb, 1024, 2048L * 1024, Kb, 1024, 2048L * 1024,
      Eb, 2048, 2048L * 2048, 1024, mask, 0.03125f, nullptr, Part);

  rowsum_inv<<<128, 256, 0, stream>>>(Part, Linv);

  // R = (E V^T) * Linv[row], bf16
  gemm256<1><<<dim3(8, 4, 16), 512, 131072, stream>>>(
      Eb, 2048, 2048L * 2048, Vb, 2048, 1024L * 2048,
      R, 1024, 2048L * 1024, 2048, nullptr, 1.f, nullptr, Linv);

  // out = R W^T + bias
  gemm256<2><<<dim3(128, 4, 1), 512, 131072, stream>>>(
      R, 1024, 0, Wb, 1024, 0,
      d_out, 1024, 0, 1024, nullptr, 1.f, bias, nullptr);
}